// Round 2
// 273.722 us; speedup vs baseline: 1.1465x; 1.1465x over previous
//
#include <hip/hip_runtime.h>

// image (8,256,64,64) f32, boxes (1000,4) f32, box_ind (1000,) i32
// out (1000,256,14,14) f32
constexpr int CROP_H = 14;
constexpr int CROP_W = 14;
constexpr int PIX    = CROP_H * CROP_W;   // 196
constexpr int IMG_C  = 256;
constexpr int IMG_H  = 64;
constexpr int IMG_W  = 64;
constexpr int N_BOX  = 1000;
constexpr int NXCD   = 8;                 // MI355X XCD count
constexpr int CPT    = IMG_C / NXCD;      // 32 channels per thread = one XCD's slice
constexpr int PIX_BLOCKS = (N_BOX * PIX + 255) / 256;  // 766

// Channel-slice k is processed only by blocks with (blockIdx.x & 7) == k, which
// the dispatcher round-robins onto XCD k. Each XCD's L2 working set is then
// 8 images x 32 channels x 16 KB = 4 MiB = exactly one XCD L2. Output stores are
// non-temporal so the 215 MB write stream doesn't evict the image slice.
__global__ __launch_bounds__(256) void CropAndResize_5669356832751_kernel(
    const float* __restrict__ image,
    const float* __restrict__ boxes,
    const int*   __restrict__ box_ind,
    float* __restrict__ out)
{
    int chunk = blockIdx.x & (NXCD - 1);          // -> XCD id (round-robin mapping)
    int bidp  = blockIdx.x >> 3;                  // pixel-block index
    int tid   = bidp * 256 + threadIdx.x;
    if (tid >= N_BOX * PIX) return;

    // tid -> (n, p=(y,x)); lanes consecutive in p => coalesced stores
    int n = tid / PIX;
    int p = tid - n * PIX;
    int y = p / CROP_W;
    int x = p - y * CROP_W;
    int c0 = chunk * CPT;

    float y1 = boxes[4 * n + 0];
    float x1 = boxes[4 * n + 1];
    float y2 = boxes[4 * n + 2];
    float x2 = boxes[4 * n + 3];
    int   b  = box_ind[n];

    const float hs = (y2 - y1) * (63.0f / 13.0f);
    const float ws = (x2 - x1) * (63.0f / 13.0f);
    float in_y = y1 * 63.0f + (float)y * hs;
    float in_x = x1 * 63.0f + (float)x * ws;

    bool oob = (in_y < 0.0f) | (in_y > 63.0f) | (in_x < 0.0f) | (in_x > 63.0f);

    float tf = floorf(in_y);
    float lf = floorf(in_x);
    int ti = (int)fminf(fmaxf(tf, 0.0f), 63.0f);
    int li = (int)fminf(fmaxf(lf, 0.0f), 63.0f);

    // Shift 2x2 window so all 4 taps are in-bounds at fixed offsets:
    // rows {row0,row0+1}, cols {col0,col0+1}. Effective lerp measured from
    // the window origin reproduces the clamped-tap semantics exactly for
    // in-bounds samples (ti==63 -> in_y==63 -> lerp_eff==1 selects row 63).
    int row0 = min(ti, 62);
    int col0 = min(li, 62);
    float yl = fminf(fmaxf(in_y, 0.0f), 63.0f) - (float)row0;
    float xl = fminf(fmaxf(in_x, 0.0f), 63.0f) - (float)col0;

    // Bilinear weights with OOB mask folded in (OOB -> all zero -> val 0)
    float m    = oob ? 0.0f : 1.0f;
    float omxl = 1.0f - xl;
    float omyl = 1.0f - yl;
    float w00 = omxl * omyl * m;
    float w01 = xl   * omyl * m;
    float w10 = omxl * yl   * m;
    float w11 = xl   * yl   * m;

    const float* src = image + ((size_t)b * IMG_C + c0) * (size_t)(IMG_H * IMG_W)
                             + row0 * IMG_W + col0;
    float* dst = out + ((size_t)n * IMG_C + c0) * (size_t)PIX + p;

#pragma unroll 8
    for (int c = 0; c < CPT; ++c) {
        float v00 = src[0];
        float v01 = src[1];
        float v10 = src[IMG_W];
        float v11 = src[IMG_W + 1];
        float v = v00 * w00 + v01 * w01 + v10 * w10 + v11 * w11;
        __builtin_nontemporal_store(v, dst);
        src += IMG_H * IMG_W;
        dst += PIX;
    }
}

extern "C" void kernel_launch(void* const* d_in, const int* in_sizes, int n_in,
                              void* d_out, int out_size, void* d_ws, size_t ws_size,
                              hipStream_t stream) {
    const float* image   = (const float*)d_in[0];
    const float* boxes   = (const float*)d_in[1];
    const int*   box_ind = (const int*)d_in[2];
    float* out = (float*)d_out;

    dim3 grid(PIX_BLOCKS * NXCD);
    CropAndResize_5669356832751_kernel<<<grid, 256, 0, stream>>>(
        image, boxes, box_ind, out);
}

// Round 3
// 271.731 us; speedup vs baseline: 1.1549x; 1.0073x over previous
//
#include <hip/hip_runtime.h>

// image (8,256,64,64) f32, boxes (1000,4) f32, box_ind (1000,) i32
// out (1000,256,14,14) f32
constexpr int CROP_H = 14;
constexpr int CROP_W = 14;
constexpr int PIX    = CROP_H * CROP_W;   // 196
constexpr int IMG_C  = 256;
constexpr int IMG_H  = 64;
constexpr int IMG_W  = 64;
constexpr int N_BOX  = 1000;
constexpr int NXCD   = 8;                 // MI355X XCD count
constexpr int NPHASE = 2;                 // temporal phases per XCD
constexpr int NSLICE = NXCD * NPHASE;     // 16 channel slices
constexpr int CPT    = IMG_C / NSLICE;    // 16 channels per thread
constexpr int PIX_BLOCKS = (N_BOX * PIX + 255) / 256;  // 766

// Channel-slice -> XCD pinning with 2x capacity slack:
//   slice s (16 channels) is processed by XCD (s & 7) during phase (s >> 3).
//   blockIdx.x = ((phase * PIX_BLOCKS + bidp) << 3) | xcd, so the dispatcher's
//   round-robin block->XCD mapping pins slices to XCDs, and phase-0 blocks
//   (first 6128) drain before phase-1 blocks start (grid >> resident capacity).
//   Per-XCD per-phase read set: 8 img x 16 ch x 16 KB = 2 MiB = 50% of the
//   4 MiB XCD L2 (round-2's exact 4 MiB fit still thrashed under the
//   concurrent 215 MB write stream). Output stores remain non-temporal.
__global__ __launch_bounds__(256) void CropAndResize_5669356832751_kernel(
    const float* __restrict__ image,
    const float* __restrict__ boxes,
    const int*   __restrict__ box_ind,
    float* __restrict__ out)
{
    int xcd  = blockIdx.x & (NXCD - 1);           // -> XCD id (round-robin mapping)
    int rest = blockIdx.x >> 3;                   // 0 .. NPHASE*PIX_BLOCKS-1
    int phase = (rest >= PIX_BLOCKS) ? 1 : 0;
    int bidp  = rest - phase * PIX_BLOCKS;        // pixel-block index
    int tid   = bidp * 256 + threadIdx.x;
    if (tid >= N_BOX * PIX) return;

    int c0 = (phase * NXCD + xcd) * CPT;          // this slice's first channel

    // tid -> (n, p=(y,x)); lanes consecutive in p => coalesced stores
    int n = tid / PIX;
    int p = tid - n * PIX;
    int y = p / CROP_W;
    int x = p - y * CROP_W;

    float y1 = boxes[4 * n + 0];
    float x1 = boxes[4 * n + 1];
    float y2 = boxes[4 * n + 2];
    float x2 = boxes[4 * n + 3];
    int   b  = box_ind[n];

    const float hs = (y2 - y1) * (63.0f / 13.0f);
    const float ws = (x2 - x1) * (63.0f / 13.0f);
    float in_y = y1 * 63.0f + (float)y * hs;
    float in_x = x1 * 63.0f + (float)x * ws;

    bool oob = (in_y < 0.0f) | (in_y > 63.0f) | (in_x < 0.0f) | (in_x > 63.0f);

    float tf = floorf(in_y);
    float lf = floorf(in_x);
    int ti = (int)fminf(fmaxf(tf, 0.0f), 63.0f);
    int li = (int)fminf(fmaxf(lf, 0.0f), 63.0f);

    // Shift 2x2 window so all 4 taps are in-bounds at fixed offsets:
    // rows {row0,row0+1}, cols {col0,col0+1}. Effective lerp measured from
    // the window origin reproduces the clamped-tap semantics exactly for
    // in-bounds samples (ti==63 -> in_y==63 -> lerp_eff==1 selects row 63).
    int row0 = min(ti, 62);
    int col0 = min(li, 62);
    float yl = fminf(fmaxf(in_y, 0.0f), 63.0f) - (float)row0;
    float xl = fminf(fmaxf(in_x, 0.0f), 63.0f) - (float)col0;

    // Bilinear weights with OOB mask folded in (OOB -> all zero -> val 0)
    float m    = oob ? 0.0f : 1.0f;
    float omxl = 1.0f - xl;
    float omyl = 1.0f - yl;
    float w00 = omxl * omyl * m;
    float w01 = xl   * omyl * m;
    float w10 = omxl * yl   * m;
    float w11 = xl   * yl   * m;

    const float* src = image + ((size_t)b * IMG_C + c0) * (size_t)(IMG_H * IMG_W)
                             + row0 * IMG_W + col0;
    float* dst = out + ((size_t)n * IMG_C + c0) * (size_t)PIX + p;

#pragma unroll
    for (int c = 0; c < CPT; ++c) {
        float v00 = src[0];
        float v01 = src[1];
        float v10 = src[IMG_W];
        float v11 = src[IMG_W + 1];
        float v = v00 * w00 + v01 * w01 + v10 * w10 + v11 * w11;
        __builtin_nontemporal_store(v, dst);
        src += IMG_H * IMG_W;
        dst += PIX;
    }
}

extern "C" void kernel_launch(void* const* d_in, const int* in_sizes, int n_in,
                              void* d_out, int out_size, void* d_ws, size_t ws_size,
                              hipStream_t stream) {
    const float* image   = (const float*)d_in[0];
    const float* boxes   = (const float*)d_in[1];
    const int*   box_ind = (const int*)d_in[2];
    float* out = (float*)d_out;

    dim3 grid(PIX_BLOCKS * NPHASE * NXCD);
    CropAndResize_5669356832751_kernel<<<grid, 256, 0, stream>>>(
        image, boxes, box_ind, out);
}